// Round 1
// baseline (270.478 us; speedup 1.0000x reference)
//
#include <hip/hip_runtime.h>
#include <math.h>

#define S 256
#define A 180
#define B 4

// Kernel 1: apply inscribed-circle mask (dist <= S/2) into workspace.
// Integer test dx^2+dy^2 <= 128^2 is exactly equivalent to sqrt(...) <= 128.
__global__ void radon_mask_kernel(const float* __restrict__ in, float* __restrict__ out) {
    int idx = blockIdx.x * 256 + threadIdx.x;        // 0 .. B*S*S-1
    int p = idx & (S * S - 1);
    int y = p >> 8;
    int x = p & 255;
    int dx = x - 128, dy = y - 128;
    float v = in[idx];
    out[idx] = (dx * dx + dy * dy <= 16384) ? v : 0.0f;
}

// Kernel 2: one block per (angle, batch); thread j accumulates ray over i.
// px(i) = 127.5 + c*(i-127.5) - s*(j-127.5)
// py(i) = 127.5 + s*(i-127.5) + c*(j-127.5)
// Bilinear, zeros padding, sum over i -> sinogram[b, a, j].
__global__ __launch_bounds__(256) void radon_ray_kernel(const float* __restrict__ img,
                                                        float* __restrict__ out) {
    const int a = blockIdx.x;   // angle
    const int b = blockIdx.y;   // batch
    const int j = threadIdx.x;  // output position

    // angles: linspace(0,180,A) degrees -> radians; step = pi/179
    float ang = (float)a * (float)(M_PI / 179.0);
    float sn, cs;
    sincosf(ang, &sn, &cs);

    float ry = (float)j - 127.5f;
    float bx = fmaf(-sn, ry, 127.5f);  // px at rx=0 offset: add cs*rx
    float by = fmaf(cs, ry, 127.5f);

    const float* __restrict__ im = img + (size_t)b * (S * S);

    float acc = 0.0f;
#pragma unroll 4
    for (int i = 0; i < S; ++i) {
        float rx = (float)i - 127.5f;
        float px = fmaf(cs, rx, bx);
        float py = fmaf(sn, rx, by);

        float x0f = floorf(px);
        float y0f = floorf(py);
        float wx = px - x0f;
        float wy = py - y0f;
        int x0 = (int)x0f;
        int y0 = (int)y0f;
        int x1 = x0 + 1;
        int y1 = y0 + 1;

        bool vx0 = (x0 >= 0) & (x0 < S);
        bool vx1 = (x1 >= 0) & (x1 < S);
        bool vy0 = (y0 >= 0) & (y0 < S);
        bool vy1 = (y1 >= 0) & (y1 < S);

        float v00 = (vx0 & vy0) ? im[y0 * S + x0] : 0.0f;
        float v10 = (vx1 & vy0) ? im[y0 * S + x1] : 0.0f;
        float v01 = (vx0 & vy1) ? im[y1 * S + x0] : 0.0f;
        float v11 = (vx1 & vy1) ? im[y1 * S + x1] : 0.0f;

        float lx0 = fmaf(wx, v10 - v00, v00);
        float lx1 = fmaf(wx, v11 - v01, v01);
        acc += fmaf(wy, lx1 - lx0, lx0);
    }

    out[((size_t)b * A + a) * S + j] = acc;
}

extern "C" void kernel_launch(void* const* d_in, const int* in_sizes, int n_in,
                              void* d_out, int out_size, void* d_ws, size_t ws_size,
                              hipStream_t stream) {
    const float* x = (const float*)d_in[0];
    float* out = (float*)d_out;
    float* masked = (float*)d_ws;  // B*S*S floats = 1 MiB

    radon_mask_kernel<<<dim3((B * S * S) / 256), dim3(256), 0, stream>>>(x, masked);
    radon_ray_kernel<<<dim3(A, B), dim3(256), 0, stream>>>(masked, out);
}